// Round 11
// baseline (383.149 us; speedup 1.0000x reference)
//
#include <hip/hip_runtime.h>
#include <hip/hip_bf16.h>
#include <cstdint>
#include <cstddef>

#define N_NODES   8000
#define D_INF     512
#define HC        1536
#define H_HEADS   3
#define C_DIM     512
#define K_NBR     6
#define KNN_EDGE  48000      // N*K
#define N_EDGE    56000      // N*K + N self loops
#define CAP       48         // max in-degree capacity
#define M_PAD     8064       // 63*128
#define NEG_SLOPE 0.2f

typedef float    f32x4  __attribute__((ext_vector_type(4)));
typedef __bf16   bf16x8 __attribute__((ext_vector_type(8)));

// ---------- workspace layout (bytes, all 256-aligned) ----------
static constexpr size_t XB_OFF  = 0;                               // bf16 [8064][512]
static constexpr size_t WT_OFF  = XB_OFF  + (size_t)M_PAD*512*2;   // bf16 [2][1536][512]
static constexpr size_t XL_OFF  = WT_OFF  + (size_t)2*1536*512*2;  // f32  [8000][1536]
static constexpr size_t XR_OFF  = XL_OFF  + (size_t)N_NODES*HC*4;  // f32  [8000][1536]
static constexpr size_t NBR_OFF = XR_OFF  + (size_t)N_NODES*HC*4;  // i32  [8000][6]
static constexpr size_t CNT_OFF = NBR_OFF + (size_t)N_NODES*K_NBR*4; // i32 [8000]
static constexpr size_t INL_OFF = CNT_OFF + (size_t)N_NODES*4;     // i32  [8000][64] (CAP=48 used, slack for safety)
static constexpr size_t XLW_OFF = INL_OFF + (size_t)N_NODES*64*4;  // f32  [8000][3][2]
static constexpr size_t CB_OFF  = XLW_OFF + (size_t)N_NODES*3*2*4; // f32  [2]
static constexpr size_t WS_NEED = CB_OFF + 256;

// ---------- helpers ----------
__device__ inline float wred_add(float v) {
#pragma unroll
  for (int off = 32; off > 0; off >>= 1) v += __shfl_xor(v, off, 64);
  return v;
}
__device__ inline float wred_max(float v) {
#pragma unroll
  for (int off = 32; off > 0; off >>= 1) v = fmaxf(v, __shfl_xor(v, off, 64));
  return v;
}
// float->bf16 round-to-nearest-even (bit-exact, no type-member dependencies)
__device__ inline unsigned short f2bf(float f) {
  unsigned u = __float_as_uint(f);
  u = u + 0x7FFFu + ((u >> 16) & 1u);
  return (unsigned short)(u >> 16);
}
__device__ inline unsigned long long umin64(unsigned long long a, unsigned long long b) {
  return a < b ? a : b;
}
__device__ inline unsigned long long umax64(unsigned long long a, unsigned long long b) {
  return a > b ? a : b;
}

#define GLOAD_LDS16(gp, lp)                                                     \
  __builtin_amdgcn_global_load_lds(                                             \
      (__attribute__((address_space(1))) void*)(void*)(gp),                     \
      (__attribute__((address_space(3))) void*)(lp), 16, 0, 0)

// ---------- K1: conversions ----------
__global__ __launch_bounds__(256) void convert_x_kernel(const float* __restrict__ x,
                                                        unsigned short* __restrict__ xb) {
  int t = blockIdx.x * 256 + threadIdx.x;         // t < 1,024,000 exact
  f32x4 v = *(const f32x4*)(x + (size_t)t * 4);
  unsigned short o[4];
#pragma unroll
  for (int j = 0; j < 4; ++j) o[j] = f2bf(v[j]);
  *(ushort4*)(xb + (size_t)t * 4) = make_ushort4(o[0], o[1], o[2], o[3]);
}

// W [512][1536] f32 -> Wt [1536][512] bf16 (transpose + convert); read-coalesced
__global__ __launch_bounds__(256) void convert_w_kernel(const float* __restrict__ W,
                                                        unsigned short* __restrict__ Wt) {
  int t = blockIdx.x * 256 + threadIdx.x;         // t < 786,432 exact
  int k = t / 1536, n = t - k * 1536;
  Wt[(size_t)n * 512 + k] = f2bf(W[t]);
}

// ---------- K2: exact-arithmetic KNN, wave-replicated top-7 ----------
// Q=1 frame (8000 waves) + float4 loads (2 candidates/lane/iter, 125->62
// latency-exposed loads) + 1-deep software prefetch. Inserts: ballot once,
// s_ff1 pops, 32-bit readlane; stale pops absorbed by min/max network
// (bit-proven r8/r9). d2 arithmetic bit-identical to passing rounds.
__global__ __launch_bounds__(256) void knn_kernel(const float* __restrict__ pos,
                                                  int* __restrict__ nbr) {
#pragma clang fp contract(off)
  const int wave = threadIdx.x >> 6, lane = threadIdx.x & 63;
  const int i = blockIdx.x * 4 + wave;            // grid 2000 -> i < 8000 exact
  const f32x4* __restrict__ p4 = (const f32x4*)pos;   // 2 points per f32x4
  const float2* __restrict__ p2 = (const float2*)pos;
  const float xi = pos[i * 2 + 0], yi = pos[i * 2 + 1];
  const float sqi = xi * xi + yi * yi;            // fl(x^2)+fl(y^2), no contract
  unsigned long long s0, s1, s2, s3, s4, s5, s6;  // ascending; s6 = threshold
  s0 = s1 = s2 = s3 = s4 = s5 = s6 = ~0ull;

#define INSERT_CV(cv)                                                           \
  do {                                                                          \
    s6 = umin64(s6, umax64(s5, (cv)));                                          \
    s5 = umin64(s5, umax64(s4, (cv)));                                          \
    s4 = umin64(s4, umax64(s3, (cv)));                                          \
    s3 = umin64(s3, umax64(s2, (cv)));                                          \
    s2 = umin64(s2, umax64(s1, (cv)));                                          \
    s1 = umin64(s1, umax64(s0, (cv)));                                          \
    s0 = umin64(s0, (cv));                                                      \
  } while (0)

  // 62 f32x4 iterations cover j < 7936 (2 candidates/lane); prefetch 1-deep.
  f32x4 cur = p4[lane];
  for (int t = 0; t < 62; ++t) {
    f32x4 nxt = cur;
    if (t < 61) nxt = p4[(t + 1) * 64 + lane];    // issue early; used next iter
    const int j0 = (t << 7) + (lane << 1);        // even candidate
    const float sq0 = cur.x * cur.x + cur.y * cur.y;   // no contract
    const float dt0 = fmaf(yi, cur.y, xi * cur.x);
    const float d20 = (sqi + sq0) - 2.0f * dt0;
    const float sq1 = cur.z * cur.z + cur.w * cur.w;
    const float dt1 = fmaf(yi, cur.w, xi * cur.z);
    const float d21 = (sqi + sq1) - 2.0f * dt1;
    unsigned u0 = __float_as_uint(d20);
    u0 ^= (unsigned)((int)u0 >> 31) | 0x80000000u;
    unsigned u1 = __float_as_uint(d21);
    u1 ^= (unsigned)((int)u1 >> 31) | 0x80000000u;
    const unsigned long long c0 = (((unsigned long long)u0) << 32) | (unsigned)j0;
    const unsigned long long c1 = (((unsigned long long)u1) << 32) | (unsigned)(j0 + 1);
    unsigned long long m = __ballot(c0 < s6) | __ballot(c1 < s6);
    while (m) {
      const int l = __ffsll(m) - 1;
      m &= m - 1;
      const int jl = (t << 7) + (l << 1);
      const unsigned v0 = __builtin_amdgcn_readlane(u0, l);
      const unsigned v1 = __builtin_amdgcn_readlane(u1, l);
      const unsigned long long cv0 = (((unsigned long long)v0) << 32) | (unsigned)jl;
      const unsigned long long cv1 = (((unsigned long long)v1) << 32) | (unsigned)(jl + 1);
      INSERT_CV(cv0);                             // stale/unqualified -> no-op
      INSERT_CV(cv1);
    }
    cur = nxt;
  }
  // epilogue: 64 candidates j = 7936 + lane
  {
    const int j = 7936 + lane;
    const float2 pj = p2[j];
    const float sqj = pj.x * pj.x + pj.y * pj.y;
    const float dot = fmaf(yi, pj.y, xi * pj.x);
    const float d2  = (sqi + sqj) - 2.0f * dot;
    unsigned u = __float_as_uint(d2);
    u ^= (unsigned)((int)u >> 31) | 0x80000000u;
    const unsigned long long c = (((unsigned long long)u) << 32) | (unsigned)j;
    unsigned long long m = __ballot(c < s6);
    while (m) {
      const int l = __ffsll(m) - 1;
      m &= m - 1;
      const unsigned v = __builtin_amdgcn_readlane(u, l);
      const unsigned long long cv =
          (((unsigned long long)v) << 32) | (unsigned)(7936 + l);
      INSERT_CV(cv);
    }
  }
#undef INSERT_CV
  if (lane == 0) {                                // drop rank-0 (self-ish)
    nbr[i * K_NBR + 0] = (int)(s1 & 0xFFFFFFFFu);
    nbr[i * K_NBR + 1] = (int)(s2 & 0xFFFFFFFFu);
    nbr[i * K_NBR + 2] = (int)(s3 & 0xFFFFFFFFu);
    nbr[i * K_NBR + 3] = (int)(s4 & 0xFFFFFFFFu);
    nbr[i * K_NBR + 4] = (int)(s5 & 0xFFFFFFFFu);
    nbr[i * K_NBR + 5] = (int)(s6 & 0xFFFFFFFFu);
  }
}

// ---------- K3: reverse adjacency (incoming edges per dst) ----------
__global__ __launch_bounds__(256) void build_inlist_kernel(const int* __restrict__ nbr,
                                                           int* __restrict__ cnt,
                                                           int* __restrict__ inlist) {
  int t = blockIdx.x * 256 + threadIdx.x;
  if (t >= N_EDGE) return;
  int d = (t < KNN_EDGE) ? nbr[t] : (t - KNN_EDGE);
  int p = atomicAdd(&cnt[d], 1);
  if (p < CAP) inlist[(size_t)d * 64 + p] = t;    // stride 64 (slack)
}

// ---------- K4: bf16 MFMA GEMM  C[M,1536] = A[M,512] * Bt[1536,512]^T + bias ----------
// 128x128 tile, BK=32, 4 waves 2x2, global_load_lds w16, XOR chunk swizzle s(r)=(r>>1)&3
__global__ __launch_bounds__(256) void gemm_kernel(const unsigned short* __restrict__ A,
                                                   const unsigned short* __restrict__ Bt,
                                                   const float* __restrict__ bias,
                                                   float* __restrict__ Cout) {
  __shared__ unsigned short As[128 * 32];
  __shared__ unsigned short Bs[128 * 32];
  const int tid = threadIdx.x, lane = tid & 63, wave = tid >> 6;
  const int bn0 = blockIdx.x * 128, bm0 = blockIdx.y * 128;
  const int wr = wave >> 1, wc = wave & 1;
  f32x4 acc[4][4];
#pragma unroll
  for (int m = 0; m < 4; ++m)
#pragma unroll
    for (int n = 0; n < 4; ++n) acc[m][n] = (f32x4)0.0f;

  const int rs = wave * 32 + (lane >> 2);          // staging row base (q adds 16)
  for (int k0 = 0; k0 < 512; k0 += 32) {
    __syncthreads();
#pragma unroll
    for (int q = 0; q < 2; ++q) {
      int r  = rs + q * 16;
      int cc = (lane & 3) ^ ((r >> 1) & 3);        // logical k-chunk for this phys slot
      GLOAD_LDS16(A  + (size_t)(bm0 + r) * 512 + k0 + cc * 8, As + (wave * 2 + q) * 512);
      GLOAD_LDS16(Bt + (size_t)(bn0 + r) * 512 + k0 + cc * 8, Bs + (wave * 2 + q) * 512);
    }
    __syncthreads();
    bf16x8 af[4], bfr[4];
#pragma unroll
    for (int m = 0; m < 4; ++m) {
      int r  = wr * 64 + m * 16 + (lane & 15);
      int sl = (lane >> 4) ^ ((r >> 1) & 3);
      af[m] = *(const bf16x8*)(As + r * 32 + sl * 8);
    }
#pragma unroll
    for (int n = 0; n < 4; ++n) {
      int r  = wc * 64 + n * 16 + (lane & 15);
      int sl = (lane >> 4) ^ ((r >> 1) & 3);
      bfr[n] = *(const bf16x8*)(Bs + r * 32 + sl * 8);
    }
#pragma unroll
    for (int m = 0; m < 4; ++m)
#pragma unroll
      for (int n = 0; n < 4; ++n)
        acc[m][n] = __builtin_amdgcn_mfma_f32_16x16x32_bf16(af[m], bfr[n], acc[m][n], 0, 0, 0);
  }
  // epilogue: D col = lane&15, row = (lane>>4)*4 + reg
#pragma unroll
  for (int n = 0; n < 4; ++n) {
    int col = bn0 + wc * 64 + n * 16 + (lane & 15);
    float bv = bias[col];
#pragma unroll
    for (int m = 0; m < 4; ++m) {
      int rbase = bm0 + wr * 64 + m * 16 + (lane >> 4) * 4;
#pragma unroll
      for (int g = 0; g < 4; ++g) {
        int row = rbase + g;
        if (row < N_NODES) Cout[(size_t)row * HC + col] = acc[m][n][g] + bv;
      }
    }
  }
}

// ---------- K5: xlW[n][h][j] = sum_c xl[n,h,c] * fcW[c,j] ----------
__global__ __launch_bounds__(256) void xlw_kernel(const float* __restrict__ xl,
                                                  const float* __restrict__ fcW,
                                                  float* __restrict__ xlW) {
  const int wave = threadIdx.x >> 6, lane = threadIdx.x & 63;
  const int idx = blockIdx.x * 4 + wave;          // < 24000 exact
  const int n = idx / 3, h = idx - n * 3;
  const float* row = xl + (size_t)n * HC + h * C_DIM + lane * 8;
  f32x4 a = *(const f32x4*)(row);
  f32x4 b = *(const f32x4*)(row + 4);
  const float* fw = fcW + lane * 16;              // [c][2] pairs for 8 c's
  float vv[8] = {a[0], a[1], a[2], a[3], b[0], b[1], b[2], b[3]};
  float s0 = 0.f, s1 = 0.f;
#pragma unroll
  for (int t = 0; t < 8; ++t) { s0 += vv[t] * fw[2 * t]; s1 += vv[t] * fw[2 * t + 1]; }
  s0 = wred_add(s0); s1 = wred_add(s1);
  if (lane == 0) { xlW[(size_t)idx * 2] = s0; xlW[(size_t)idx * 2 + 1] = s1; }
}

__global__ void const2_kernel(const float* __restrict__ gb, const float* __restrict__ fcW,
                              const float* __restrict__ fcb, float* __restrict__ cb) {
  const int lane = threadIdx.x;                   // block 64
  const float* g = gb + lane * 8;
  const float* fw = fcW + lane * 16;
  float s0 = 0.f, s1 = 0.f;
#pragma unroll
  for (int t = 0; t < 8; ++t) { s0 += g[t] * fw[2 * t]; s1 += g[t] * fw[2 * t + 1]; }
  s0 = wred_add(s0); s1 = wred_add(s1);
  if (lane == 0) { cb[0] = s0 + fcb[0]; cb[1] = s1 + fcb[1]; }
}

// ---------- K6: per-dst e-values + softmax + aggregate + fc ----------
__global__ __launch_bounds__(256) void attn_kernel(const float* __restrict__ xl,
                                                   const float* __restrict__ xr,
                                                   const float* __restrict__ att,
                                                   const int* __restrict__ cnt,
                                                   const int* __restrict__ inlist,
                                                   const float* __restrict__ xlW,
                                                   const float* __restrict__ cb,
                                                   float* __restrict__ out) {
  __shared__ float esh[4][CAP * 3];
  const int wave = threadIdx.x >> 6, lane = threadIdx.x & 63;
  const int d = blockIdx.x * 4 + wave;            // grid 2000 -> d < 8000 exact
  const int c0 = lane * 8;
  float attf[3][8], xrf[3][8];
#pragma unroll
  for (int h = 0; h < 3; ++h) {
    f32x4 a = *(const f32x4*)(att + h * C_DIM + c0);
    f32x4 b = *(const f32x4*)(att + h * C_DIM + c0 + 4);
    f32x4 p = *(const f32x4*)(xr + (size_t)d * HC + h * C_DIM + c0);
    f32x4 q = *(const f32x4*)(xr + (size_t)d * HC + h * C_DIM + c0 + 4);
#pragma unroll
    for (int j = 0; j < 4; ++j) {
      attf[h][j] = a[j]; attf[h][4 + j] = b[j];
      xrf[h][j]  = p[j]; xrf[h][4 + j]  = q[j];
    }
  }
  int cn = cnt[d]; if (cn > CAP) cn = CAP;
  for (int t = 0; t < cn; ++t) {
    int id = inlist[(size_t)d * 64 + t];
    int s  = (id < KNN_EDGE) ? (id / K_NBR) : (id - KNN_EDGE);
    const float* xrow = xl + (size_t)s * HC + c0;
#pragma unroll
    for (int h = 0; h < 3; ++h) {
      f32x4 a = *(const f32x4*)(xrow + h * C_DIM);
      f32x4 b = *(const f32x4*)(xrow + h * C_DIM + 4);
      float p = 0.f;
#pragma unroll
      for (int j = 0; j < 4; ++j) {
        float v = xrf[h][j] + a[j];
        v = (v >= 0.f) ? v : v * NEG_SLOPE;
        p += v * attf[h][j];
      }
#pragma unroll
      for (int j = 0; j < 4; ++j) {
        float v = xrf[h][4 + j] + b[j];
        v = (v >= 0.f) ? v : v * NEG_SLOPE;
        p += v * attf[h][4 + j];
      }
      p = wred_add(p);
      if (lane == 0) esh[wave][t * 3 + h] = p;
    }
  }
  // softmax over incoming edges (lane = edge slot) + weighted xlW aggregation
  int idl = (lane < cn) ? inlist[(size_t)d * 64 + lane] : 0;
  int sl  = (idl < KNN_EDGE) ? (idl / K_NBR) : (idl - KNN_EDGE);
  float o0 = 0.f, o1 = 0.f;
#pragma unroll
  for (int h = 0; h < 3; ++h) {
    float ev = (lane < cn) ? esh[wave][lane * 3 + h] : -__builtin_inff();
    float mx = wred_max(ev);
    float ex = (lane < cn) ? expf(ev - mx) : 0.f;
    float ss = wred_add(ex);
    float alpha = ex / (ss + 1e-16f);
    float w0 = (lane < cn) ? xlW[((size_t)sl * 3 + h) * 2]     * alpha : 0.f;
    float w1 = (lane < cn) ? xlW[((size_t)sl * 3 + h) * 2 + 1] * alpha : 0.f;
    o0 += wred_add(w0);
    o1 += wred_add(w1);
  }
  if (lane == 0) {
    out[d * 2]     = o0 * (1.0f / 3.0f) + cb[0];
    out[d * 2 + 1] = o1 * (1.0f / 3.0f) + cb[1];
  }
}

// ---------- launch ----------
extern "C" void kernel_launch(void* const* d_in, const int* in_sizes, int n_in,
                              void* d_out, int out_size, void* d_ws, size_t ws_size,
                              hipStream_t stream) {
  const float* feature  = (const float*)d_in[0];
  const float* position = (const float*)d_in[1];
  const float* W_l      = (const float*)d_in[2];
  const float* b_l      = (const float*)d_in[3];
  const float* W_r      = (const float*)d_in[4];
  const float* b_r      = (const float*)d_in[5];
  const float* att      = (const float*)d_in[6];
  const float* gat_bias = (const float*)d_in[7];
  const float* fc_W     = (const float*)d_in[8];
  const float* fc_b     = (const float*)d_in[9];
  float* out = (float*)d_out;

  if (ws_size < WS_NEED) return;  // need ~112.2 MB scratch

  uint8_t* ws = (uint8_t*)d_ws;
  unsigned short* xb  = (unsigned short*)(ws + XB_OFF);
  unsigned short* wt0 = (unsigned short*)(ws + WT_OFF);
  unsigned short* wt1 = wt0 + (size_t)1536 * 512;
  float* xl   = (float*)(ws + XL_OFF);
  float* xr   = (float*)(ws + XR_OFF);
  int*   nbr  = (int*)(ws + NBR_OFF);
  int*   cnt  = (int*)(ws + CNT_OFF);
  int*   inl  = (int*)(ws + INL_OFF);
  float* xlW  = (float*)(ws + XLW_OFF);
  float* cb   = (float*)(ws + CB_OFF);

  hipMemsetAsync(cnt, 0, (size_t)N_NODES * 4, stream);

  convert_x_kernel<<<4000, 256, 0, stream>>>(feature, xb);
  convert_w_kernel<<<3072, 256, 0, stream>>>(W_l, wt0);
  convert_w_kernel<<<3072, 256, 0, stream>>>(W_r, wt1);
  knn_kernel<<<2000, 256, 0, stream>>>(position, nbr);
  build_inlist_kernel<<<219, 256, 0, stream>>>(nbr, cnt, inl);
  gemm_kernel<<<dim3(12, 63), 256, 0, stream>>>(xb, wt0, b_l, xl);
  gemm_kernel<<<dim3(12, 63), 256, 0, stream>>>(xb, wt1, b_r, xr);
  xlw_kernel<<<6000, 256, 0, stream>>>(xl, fc_W, xlW);
  const2_kernel<<<1, 64, 0, stream>>>(gat_bias, fc_W, fc_b, cb);
  attn_kernel<<<2000, 256, 0, stream>>>(xl, xr, att, cnt, inl, xlW, cb, out);
}

// Round 12
// 339.880 us; speedup vs baseline: 1.1273x; 1.1273x over previous
//
#include <hip/hip_runtime.h>
#include <hip/hip_bf16.h>
#include <cstdint>
#include <cstddef>

#define N_NODES   8000
#define D_INF     512
#define HC        1536
#define H_HEADS   3
#define C_DIM     512
#define K_NBR     6
#define KNN_EDGE  48000      // N*K
#define N_EDGE    56000      // N*K + N self loops
#define CAP       48         // max in-degree capacity
#define M_PAD     8064       // 63*128
#define NEG_SLOPE 0.2f

typedef float    f32x4  __attribute__((ext_vector_type(4)));
typedef __bf16   bf16x8 __attribute__((ext_vector_type(8)));

// ---------- workspace layout (bytes, all 256-aligned) ----------
static constexpr size_t XB_OFF  = 0;                               // bf16 [8064][512]
static constexpr size_t WT_OFF  = XB_OFF  + (size_t)M_PAD*512*2;   // bf16 [2][1536][512]
static constexpr size_t XL_OFF  = WT_OFF  + (size_t)2*1536*512*2;  // f32  [8000][1536]
static constexpr size_t XR_OFF  = XL_OFF  + (size_t)N_NODES*HC*4;  // f32  [8000][1536]
static constexpr size_t NBR_OFF = XR_OFF  + (size_t)N_NODES*HC*4;  // i32  [8000][6]
static constexpr size_t CNT_OFF = NBR_OFF + (size_t)N_NODES*K_NBR*4; // i32 [8000]
static constexpr size_t INL_OFF = CNT_OFF + (size_t)N_NODES*4;     // i32  [8000][64]
static constexpr size_t XLW_OFF = INL_OFF + (size_t)N_NODES*64*4;  // f32  [8000][3][2]
static constexpr size_t CB_OFF  = XLW_OFF + (size_t)N_NODES*3*2*4; // f32  [2]
static constexpr size_t EV_OFF  = CB_OFF  + 256;                   // f32  [56000][3]
static constexpr size_t WS_NEED = EV_OFF  + (size_t)N_EDGE*3*4 + 256;

// ---------- helpers ----------
__device__ inline float wred_add(float v) {
#pragma unroll
  for (int off = 32; off > 0; off >>= 1) v += __shfl_xor(v, off, 64);
  return v;
}
__device__ inline float wred_max(float v) {
#pragma unroll
  for (int off = 32; off > 0; off >>= 1) v = fmaxf(v, __shfl_xor(v, off, 64));
  return v;
}
// float->bf16 round-to-nearest-even
__device__ inline unsigned short f2bf(float f) {
  unsigned u = __float_as_uint(f);
  u = u + 0x7FFFu + ((u >> 16) & 1u);
  return (unsigned short)(u >> 16);
}
__device__ inline unsigned long long umin64(unsigned long long a, unsigned long long b) {
  return a < b ? a : b;
}
__device__ inline unsigned long long umax64(unsigned long long a, unsigned long long b) {
  return a > b ? a : b;
}

#define GLOAD_LDS16(gp, lp)                                                     \
  __builtin_amdgcn_global_load_lds(                                             \
      (__attribute__((address_space(1))) void*)(void*)(gp),                     \
      (__attribute__((address_space(3))) void*)(lp), 16, 0, 0)

// ---------- K1: conversions ----------
__global__ __launch_bounds__(256) void convert_x_kernel(const float* __restrict__ x,
                                                        unsigned short* __restrict__ xb) {
  int t = blockIdx.x * 256 + threadIdx.x;         // t < 1,024,000 exact
  f32x4 v = *(const f32x4*)(x + (size_t)t * 4);
  unsigned short o[4];
#pragma unroll
  for (int j = 0; j < 4; ++j) o[j] = f2bf(v[j]);
  *(ushort4*)(xb + (size_t)t * 4) = make_ushort4(o[0], o[1], o[2], o[3]);
}

// W [512][1536] f32 -> Wt [1536][512] bf16 (transpose + convert); read-coalesced
__global__ __launch_bounds__(256) void convert_w_kernel(const float* __restrict__ W,
                                                        unsigned short* __restrict__ Wt) {
  int t = blockIdx.x * 256 + threadIdx.x;         // t < 786,432 exact
  int k = t / 1536, n = t - k * 1536;
  Wt[(size_t)n * 512 + k] = f2bf(W[t]);
}

// ---------- K2: exact-arithmetic KNN, wave-replicated top-7 (r9 form) ----------
// Q=1, 8000 waves; ballot once per chunk, s_ff1 pops + 32-bit readlane;
// stale pops absorbed by min/max network. Bit-proven r8/r9, 109.6 us.
__global__ __launch_bounds__(256) void knn_kernel(const float* __restrict__ pos,
                                                  int* __restrict__ nbr) {
#pragma clang fp contract(off)
  const int wave = threadIdx.x >> 6, lane = threadIdx.x & 63;
  const int i = blockIdx.x * 4 + wave;            // grid 2000 -> i < 8000 exact
  const float2* __restrict__ p2 = (const float2*)pos;
  const float xi = pos[i * 2 + 0], yi = pos[i * 2 + 1];
  const float sqi = xi * xi + yi * yi;            // fl(x^2)+fl(y^2), no contract
  unsigned long long s0, s1, s2, s3, s4, s5, s6;  // ascending; s6 = threshold
  s0 = s1 = s2 = s3 = s4 = s5 = s6 = ~0ull;
  for (int t = 0; t < 125; ++t) {                 // 8000 = 125*64, uniform
    const int j = (t << 6) + lane;
    const float2 pj = p2[j];
    const float sqj = pj.x * pj.x + pj.y * pj.y;  // fl(x^2)+fl(y^2), no contract
    const float dot = fmaf(yi, pj.y, xi * pj.x);  // BLAS-style k-ascending fma
    const float d2  = (sqi + sqj) - 2.0f * dot;
    unsigned u = __float_as_uint(d2);
    u ^= (unsigned)((int)u >> 31) | 0x80000000u;  // sortable bits (handles d2<0)
    const unsigned long long c = (((unsigned long long)u) << 32) | (unsigned)j;
    unsigned long long m = __ballot(c < s6);      // ballot ONCE per chunk
    while (m) {
      const int l = __ffsll(m) - 1;
      m &= m - 1;
      const unsigned cvh = __builtin_amdgcn_readlane(u, l);
      const unsigned long long cv =
          (((unsigned long long)cvh) << 32) | (unsigned)((t << 6) + l);
      // downward predicated insert: new[k] = min(s[k], max(s[k-1], cv));
      // if cv >= s6 (stale pop) the whole network is a no-op.
      s6 = umin64(s6, umax64(s5, cv));
      s5 = umin64(s5, umax64(s4, cv));
      s4 = umin64(s4, umax64(s3, cv));
      s3 = umin64(s3, umax64(s2, cv));
      s2 = umin64(s2, umax64(s1, cv));
      s1 = umin64(s1, umax64(s0, cv));
      s0 = umin64(s0, cv);
    }
  }
  if (lane == 0) {                                // drop rank-0 (self-ish)
    nbr[i * K_NBR + 0] = (int)(s1 & 0xFFFFFFFFu);
    nbr[i * K_NBR + 1] = (int)(s2 & 0xFFFFFFFFu);
    nbr[i * K_NBR + 2] = (int)(s3 & 0xFFFFFFFFu);
    nbr[i * K_NBR + 3] = (int)(s4 & 0xFFFFFFFFu);
    nbr[i * K_NBR + 4] = (int)(s5 & 0xFFFFFFFFu);
    nbr[i * K_NBR + 5] = (int)(s6 & 0xFFFFFFFFu);
  }
}

// ---------- K3: reverse adjacency (incoming edges per dst) ----------
__global__ __launch_bounds__(256) void build_inlist_kernel(const int* __restrict__ nbr,
                                                           int* __restrict__ cnt,
                                                           int* __restrict__ inlist) {
  int t = blockIdx.x * 256 + threadIdx.x;
  if (t >= N_EDGE) return;
  int d = (t < KNN_EDGE) ? nbr[t] : (t - KNN_EDGE);
  int p = atomicAdd(&cnt[d], 1);
  if (p < CAP) inlist[(size_t)d * 64 + p] = t;    // stride 64 (slack)
}

// ---------- K4: bf16 MFMA GEMM  C[M,1536] = A[M,512] * Bt[1536,512]^T + bias ----------
__global__ __launch_bounds__(256) void gemm_kernel(const unsigned short* __restrict__ A,
                                                   const unsigned short* __restrict__ Bt,
                                                   const float* __restrict__ bias,
                                                   float* __restrict__ Cout) {
  __shared__ unsigned short As[128 * 32];
  __shared__ unsigned short Bs[128 * 32];
  const int tid = threadIdx.x, lane = tid & 63, wave = tid >> 6;
  const int bn0 = blockIdx.x * 128, bm0 = blockIdx.y * 128;
  const int wr = wave >> 1, wc = wave & 1;
  f32x4 acc[4][4];
#pragma unroll
  for (int m = 0; m < 4; ++m)
#pragma unroll
    for (int n = 0; n < 4; ++n) acc[m][n] = (f32x4)0.0f;

  const int rs = wave * 32 + (lane >> 2);          // staging row base (q adds 16)
  for (int k0 = 0; k0 < 512; k0 += 32) {
    __syncthreads();
#pragma unroll
    for (int q = 0; q < 2; ++q) {
      int r  = rs + q * 16;
      int cc = (lane & 3) ^ ((r >> 1) & 3);        // logical k-chunk for this phys slot
      GLOAD_LDS16(A  + (size_t)(bm0 + r) * 512 + k0 + cc * 8, As + (wave * 2 + q) * 512);
      GLOAD_LDS16(Bt + (size_t)(bn0 + r) * 512 + k0 + cc * 8, Bs + (wave * 2 + q) * 512);
    }
    __syncthreads();
    bf16x8 af[4], bfr[4];
#pragma unroll
    for (int m = 0; m < 4; ++m) {
      int r  = wr * 64 + m * 16 + (lane & 15);
      int sl = (lane >> 4) ^ ((r >> 1) & 3);
      af[m] = *(const bf16x8*)(As + r * 32 + sl * 8);
    }
#pragma unroll
    for (int n = 0; n < 4; ++n) {
      int r  = wc * 64 + n * 16 + (lane & 15);
      int sl = (lane >> 4) ^ ((r >> 1) & 3);
      bfr[n] = *(const bf16x8*)(Bs + r * 32 + sl * 8);
    }
#pragma unroll
    for (int m = 0; m < 4; ++m)
#pragma unroll
      for (int n = 0; n < 4; ++n)
        acc[m][n] = __builtin_amdgcn_mfma_f32_16x16x32_bf16(af[m], bfr[n], acc[m][n], 0, 0, 0);
  }
  // epilogue: D col = lane&15, row = (lane>>4)*4 + reg
#pragma unroll
  for (int n = 0; n < 4; ++n) {
    int col = bn0 + wc * 64 + n * 16 + (lane & 15);
    float bv = bias[col];
#pragma unroll
    for (int m = 0; m < 4; ++m) {
      int rbase = bm0 + wr * 64 + m * 16 + (lane >> 4) * 4;
#pragma unroll
      for (int g = 0; g < 4; ++g) {
        int row = rbase + g;
        if (row < N_NODES) Cout[(size_t)row * HC + col] = acc[m][n][g] + bv;
      }
    }
  }
}

// ---------- K5: xlW[n][h][j] = sum_c xl[n,h,c] * fcW[c,j] ----------
__global__ __launch_bounds__(256) void xlw_kernel(const float* __restrict__ xl,
                                                  const float* __restrict__ fcW,
                                                  float* __restrict__ xlW) {
  const int wave = threadIdx.x >> 6, lane = threadIdx.x & 63;
  const int idx = blockIdx.x * 4 + wave;          // < 24000 exact
  const int n = idx / 3, h = idx - n * 3;
  const float* row = xl + (size_t)n * HC + h * C_DIM + lane * 8;
  f32x4 a = *(const f32x4*)(row);
  f32x4 b = *(const f32x4*)(row + 4);
  const float* fw = fcW + lane * 16;              // [c][2] pairs for 8 c's
  float vv[8] = {a[0], a[1], a[2], a[3], b[0], b[1], b[2], b[3]};
  float s0 = 0.f, s1 = 0.f;
#pragma unroll
  for (int t = 0; t < 8; ++t) { s0 += vv[t] * fw[2 * t]; s1 += vv[t] * fw[2 * t + 1]; }
  s0 = wred_add(s0); s1 = wred_add(s1);
  if (lane == 0) { xlW[(size_t)idx * 2] = s0; xlW[(size_t)idx * 2 + 1] = s1; }
}

__global__ void const2_kernel(const float* __restrict__ gb, const float* __restrict__ fcW,
                              const float* __restrict__ fcb, float* __restrict__ cb) {
  const int lane = threadIdx.x;                   // block 64
  const float* g = gb + lane * 8;
  const float* fw = fcW + lane * 16;
  float s0 = 0.f, s1 = 0.f;
#pragma unroll
  for (int t = 0; t < 8; ++t) { s0 += g[t] * fw[2 * t]; s1 += g[t] * fw[2 * t + 1]; }
  s0 = wred_add(s0); s1 = wred_add(s1);
  if (lane == 0) { cb[0] = s0 + fcb[0]; cb[1] = s1 + fcb[1]; }
}

// ---------- K6a: edge-parallel e-values (one wave per edge) ----------
// e[edge][h] = sum_c leaky(xr[dst]+xl[src]) * att[h]; arithmetic order
// identical to the old per-dst loop -> bit-identical e-values.
__global__ __launch_bounds__(256) void edge_e_kernel(const float* __restrict__ xl,
                                                     const float* __restrict__ xr,
                                                     const float* __restrict__ att,
                                                     const int* __restrict__ nbr,
                                                     float* __restrict__ eval) {
  const int wave = threadIdx.x >> 6, lane = threadIdx.x & 63;
  const int e = blockIdx.x * 4 + wave;            // grid 14000 -> e < 56000 exact
  const int s = (e < KNN_EDGE) ? (e / K_NBR) : (e - KNN_EDGE);
  const int d = (e < KNN_EDGE) ? nbr[e] : (e - KNN_EDGE);
  const int c0 = lane * 8;
  float o[3];
#pragma unroll
  for (int h = 0; h < 3; ++h) {
    const float* xla = xl + (size_t)s * HC + h * C_DIM + c0;
    const float* xra = xr + (size_t)d * HC + h * C_DIM + c0;
    const float* ata = att + h * C_DIM + c0;
    f32x4 a0 = *(const f32x4*)(xla);
    f32x4 a1 = *(const f32x4*)(xla + 4);
    f32x4 r0 = *(const f32x4*)(xra);
    f32x4 r1 = *(const f32x4*)(xra + 4);
    f32x4 t0 = *(const f32x4*)(ata);
    f32x4 t1 = *(const f32x4*)(ata + 4);
    float p = 0.f;
#pragma unroll
    for (int j = 0; j < 4; ++j) {
      float v = r0[j] + a0[j];
      v = (v >= 0.f) ? v : v * NEG_SLOPE;
      p += v * t0[j];
    }
#pragma unroll
    for (int j = 0; j < 4; ++j) {
      float v = r1[j] + a1[j];
      v = (v >= 0.f) ? v : v * NEG_SLOPE;
      p += v * t1[j];
    }
    o[h] = wred_add(p);
  }
  if (lane == 0) {
    eval[(size_t)e * 3 + 0] = o[0];
    eval[(size_t)e * 3 + 1] = o[1];
    eval[(size_t)e * 3 + 2] = o[2];
  }
}

// ---------- K6b: per-dst softmax + xlW aggregation + fc ----------
__global__ __launch_bounds__(256) void softmax_agg_kernel(const int* __restrict__ cnt,
                                                          const int* __restrict__ inlist,
                                                          const float* __restrict__ eval,
                                                          const float* __restrict__ xlW,
                                                          const float* __restrict__ cb,
                                                          float* __restrict__ out) {
  const int wave = threadIdx.x >> 6, lane = threadIdx.x & 63;
  const int d = blockIdx.x * 4 + wave;            // grid 2000 -> d < 8000 exact
  int cn = cnt[d]; if (cn > CAP) cn = CAP;
  int idl = (lane < cn) ? inlist[(size_t)d * 64 + lane] : 0;
  int sl  = (idl < KNN_EDGE) ? (idl / K_NBR) : (idl - KNN_EDGE);
  float o0 = 0.f, o1 = 0.f;
#pragma unroll
  for (int h = 0; h < 3; ++h) {
    float ev = (lane < cn) ? eval[(size_t)idl * 3 + h] : -__builtin_inff();
    float mx = wred_max(ev);
    float ex = (lane < cn) ? expf(ev - mx) : 0.f;
    float ss = wred_add(ex);
    float alpha = ex / (ss + 1e-16f);
    float w0 = (lane < cn) ? xlW[((size_t)sl * 3 + h) * 2]     * alpha : 0.f;
    float w1 = (lane < cn) ? xlW[((size_t)sl * 3 + h) * 2 + 1] * alpha : 0.f;
    o0 += wred_add(w0);
    o1 += wred_add(w1);
  }
  if (lane == 0) {
    out[d * 2]     = o0 * (1.0f / 3.0f) + cb[0];
    out[d * 2 + 1] = o1 * (1.0f / 3.0f) + cb[1];
  }
}

// ---------- launch ----------
extern "C" void kernel_launch(void* const* d_in, const int* in_sizes, int n_in,
                              void* d_out, int out_size, void* d_ws, size_t ws_size,
                              hipStream_t stream) {
  const float* feature  = (const float*)d_in[0];
  const float* position = (const float*)d_in[1];
  const float* W_l      = (const float*)d_in[2];
  const float* b_l      = (const float*)d_in[3];
  const float* W_r      = (const float*)d_in[4];
  const float* b_r      = (const float*)d_in[5];
  const float* att      = (const float*)d_in[6];
  const float* gat_bias = (const float*)d_in[7];
  const float* fc_W     = (const float*)d_in[8];
  const float* fc_b     = (const float*)d_in[9];
  float* out = (float*)d_out;

  if (ws_size < WS_NEED) return;  // need ~112.9 MB scratch

  uint8_t* ws = (uint8_t*)d_ws;
  unsigned short* xb  = (unsigned short*)(ws + XB_OFF);
  unsigned short* wt0 = (unsigned short*)(ws + WT_OFF);
  unsigned short* wt1 = wt0 + (size_t)1536 * 512;
  float* xl   = (float*)(ws + XL_OFF);
  float* xr   = (float*)(ws + XR_OFF);
  int*   nbr  = (int*)(ws + NBR_OFF);
  int*   cnt  = (int*)(ws + CNT_OFF);
  int*   inl  = (int*)(ws + INL_OFF);
  float* xlW  = (float*)(ws + XLW_OFF);
  float* cb   = (float*)(ws + CB_OFF);
  float* ev   = (float*)(ws + EV_OFF);

  hipMemsetAsync(cnt, 0, (size_t)N_NODES * 4, stream);

  convert_x_kernel<<<4000, 256, 0, stream>>>(feature, xb);
  convert_w_kernel<<<3072, 256, 0, stream>>>(W_l, wt0);
  convert_w_kernel<<<3072, 256, 0, stream>>>(W_r, wt1);
  knn_kernel<<<2000, 256, 0, stream>>>(position, nbr);
  build_inlist_kernel<<<219, 256, 0, stream>>>(nbr, cnt, inl);
  gemm_kernel<<<dim3(12, 63), 256, 0, stream>>>(xb, wt0, b_l, xl);
  gemm_kernel<<<dim3(12, 63), 256, 0, stream>>>(xb, wt1, b_r, xr);
  xlw_kernel<<<6000, 256, 0, stream>>>(xl, fc_W, xlW);
  const2_kernel<<<1, 64, 0, stream>>>(gat_bias, fc_W, fc_b, cb);
  edge_e_kernel<<<14000, 256, 0, stream>>>(xl, xr, att, nbr, ev);
  softmax_agg_kernel<<<2000, 256, 0, stream>>>(cnt, inl, ev, xlW, cb, out);
}

// Round 14
// 305.571 us; speedup vs baseline: 1.2539x; 1.1123x over previous
//
#include <hip/hip_runtime.h>
#include <hip/hip_bf16.h>
#include <cstdint>
#include <cstddef>

#define N_NODES   8000
#define D_INF     512
#define HC        1536
#define H_HEADS   3
#define C_DIM     512
#define K_NBR     6
#define KNN_EDGE  48000      // N*K
#define N_EDGE    56000      // N*K + N self loops
#define CAP       48         // max in-degree capacity
#define M_PAD     8064       // 63*128
#define NEG_SLOPE 0.2f
#define GRID_G    32
#define H_CELL    0.03125f   // 1/32

typedef float    f32x4  __attribute__((ext_vector_type(4)));
typedef __bf16   bf16x8 __attribute__((ext_vector_type(8)));

// ---------- workspace layout (bytes, all 256-aligned) ----------
static constexpr size_t XB_OFF   = 0;                               // bf16 [8064][512]
static constexpr size_t WT_OFF   = XB_OFF  + (size_t)M_PAD*512*2;   // bf16 [2][1536][512]
static constexpr size_t XL_OFF   = WT_OFF  + (size_t)2*1536*512*2;  // f32  [8000][1536]
static constexpr size_t XR_OFF   = XL_OFF  + (size_t)N_NODES*HC*4;  // f32  [8000][1536]
static constexpr size_t NBR_OFF  = XR_OFF  + (size_t)N_NODES*HC*4;  // i32  [8000][6]
static constexpr size_t CNT_OFF  = NBR_OFF + (size_t)N_NODES*K_NBR*4; // i32 [8000]
static constexpr size_t INL_OFF  = CNT_OFF + (size_t)N_NODES*4;     // i32  [8000][64]
static constexpr size_t XLW_OFF  = INL_OFF + (size_t)N_NODES*64*4;  // f32  [8000][3][2]
static constexpr size_t CB_OFF   = XLW_OFF + (size_t)N_NODES*3*2*4; // f32  [2]
static constexpr size_t EV_OFF   = CB_OFF  + 256;                   // f32  [56000][3]
static constexpr size_t CCNT_OFF = EV_OFF  + (size_t)N_EDGE*3*4 + 256; // i32 [1024]
static constexpr size_t CST_OFF  = CCNT_OFF + 1024*4;               // i32  [1025] (+pad)
static constexpr size_t SLOT_OFF = CST_OFF  + 4352;                 // i32  [8000]
static constexpr size_t SIDX_OFF = SLOT_OFF + (size_t)N_NODES*4;    // i32  [8000]
static constexpr size_t SXY_OFF  = SIDX_OFF + (size_t)N_NODES*4;    // f32  [8000][2]
static constexpr size_t WS_NEED  = SXY_OFF  + (size_t)N_NODES*2*4 + 256;

// ---------- helpers ----------
__device__ inline float wred_add(float v) {
#pragma unroll
  for (int off = 32; off > 0; off >>= 1) v += __shfl_xor(v, off, 64);
  return v;
}
__device__ inline float wred_max(float v) {
#pragma unroll
  for (int off = 32; off > 0; off >>= 1) v = fmaxf(v, __shfl_xor(v, off, 64));
  return v;
}
// float->bf16 round-to-nearest-even
__device__ inline unsigned short f2bf(float f) {
  unsigned u = __float_as_uint(f);
  u = u + 0x7FFFu + ((u >> 16) & 1u);
  return (unsigned short)(u >> 16);
}
__device__ inline unsigned long long umin64(unsigned long long a, unsigned long long b) {
  return a < b ? a : b;
}
__device__ inline unsigned long long umax64(unsigned long long a, unsigned long long b) {
  return a > b ? a : b;
}
__device__ inline unsigned sortbits(float d) {
  unsigned u = __float_as_uint(d);
  u ^= (unsigned)((int)u >> 31) | 0x80000000u;
  return u;
}

#define GLOAD_LDS16(gp, lp)                                                     \
  __builtin_amdgcn_global_load_lds(                                             \
      (__attribute__((address_space(1))) void*)(void*)(gp),                     \
      (__attribute__((address_space(3))) void*)(lp), 16, 0, 0)

// ---------- K1: conversions ----------
__global__ __launch_bounds__(256) void convert_x_kernel(const float* __restrict__ x,
                                                        unsigned short* __restrict__ xb) {
  int t = blockIdx.x * 256 + threadIdx.x;         // t < 1,024,000 exact
  f32x4 v = *(const f32x4*)(x + (size_t)t * 4);
  unsigned short o[4];
#pragma unroll
  for (int j = 0; j < 4; ++j) o[j] = f2bf(v[j]);
  *(ushort4*)(xb + (size_t)t * 4) = make_ushort4(o[0], o[1], o[2], o[3]);
}

// W [512][1536] f32 -> Wt [1536][512] bf16 (transpose + convert)
__global__ __launch_bounds__(256) void convert_w_kernel(const float* __restrict__ W,
                                                        unsigned short* __restrict__ Wt) {
  int t = blockIdx.x * 256 + threadIdx.x;         // t < 786,432 exact
  int k = t / 1536, n = t - k * 1536;
  Wt[(size_t)n * 512 + k] = f2bf(W[t]);
}

// ---------- K2a: cell histogram ----------
__global__ __launch_bounds__(256) void cellcnt_kernel(const float* __restrict__ pos,
                                                      int* __restrict__ cellCnt,
                                                      int* __restrict__ slot) {
  int t = blockIdx.x * 256 + threadIdx.x;
  if (t >= N_NODES) return;
  float x = pos[t * 2 + 0], y = pos[t * 2 + 1];
  int cx = (int)(x * GRID_G); cx = cx < 0 ? 0 : (cx > 31 ? 31 : cx);
  int cy = (int)(y * GRID_G); cy = cy < 0 ? 0 : (cy > 31 ? 31 : cy);
  slot[t] = atomicAdd(&cellCnt[cy * GRID_G + cx], 1);
}

// ---------- K2b: exclusive scan over 1024 cells (single block) ----------
__global__ __launch_bounds__(256) void scan_kernel(const int* __restrict__ cellCnt,
                                                   int* __restrict__ cellStart) {
  __shared__ int A[1024], B[1024];
  const int tid = threadIdx.x;
  for (int i = tid; i < 1024; i += 256) A[i] = cellCnt[i];
  __syncthreads();
  int* src = A; int* dst = B;
  for (int off = 1; off < 1024; off <<= 1) {
    for (int i = tid; i < 1024; i += 256)
      dst[i] = src[i] + ((i >= off) ? src[i - off] : 0);
    __syncthreads();
    int* tp = src; src = dst; dst = tp;
  }
  for (int i = tid; i < 1024; i += 256) cellStart[i] = i ? src[i - 1] : 0;
  if (tid == 0) cellStart[1024] = src[1023];
}

// ---------- K2c: scatter into CSR ----------
__global__ __launch_bounds__(256) void scatter_kernel(const float* __restrict__ pos,
                                                      const int* __restrict__ cellStart,
                                                      const int* __restrict__ slot,
                                                      int* __restrict__ sortIdx,
                                                      float* __restrict__ sortXY) {
  int t = blockIdx.x * 256 + threadIdx.x;
  if (t >= N_NODES) return;
  float x = pos[t * 2 + 0], y = pos[t * 2 + 1];
  int cx = (int)(x * GRID_G); cx = cx < 0 ? 0 : (cx > 31 ? 31 : cx);
  int cy = (int)(y * GRID_G); cy = cy < 0 ? 0 : (cy > 31 ? 31 : cy);
  int dst = cellStart[cy * GRID_G + cx] + slot[t];
  sortIdx[dst] = t;
  sortXY[dst * 2 + 0] = x;
  sortXY[dst * 2 + 1] = y;
}

// ---------- K2d: exact binned KNN (one thread per query) ----------
// Ring search with strict conservative bound: unprocessed points at ring>=r
// have true d >= (r-1)*h, so when ((r-1)h)^2*0.999-1e-6 > d2(s6) nothing can
// displace the list -> selection == brute force. d2 formula + lexicographic
// (d2bits,j) selection copied verbatim from the bit-proven r9 kernel.
__global__ __launch_bounds__(256) void knn_kernel(const float* __restrict__ pos,
                                                  const int* __restrict__ cellStart,
                                                  const int* __restrict__ sortIdx,
                                                  const float* __restrict__ sortXY,
                                                  int* __restrict__ nbr) {
#pragma clang fp contract(off)
  int i = blockIdx.x * 256 + threadIdx.x;
  if (i >= N_NODES) return;
  const float xi = pos[i * 2 + 0], yi = pos[i * 2 + 1];
  const float sqi = xi * xi + yi * yi;            // fl(x^2)+fl(y^2), no contract
  int cx = (int)(xi * GRID_G); cx = cx < 0 ? 0 : (cx > 31 ? 31 : cx);
  int cy = (int)(yi * GRID_G); cy = cy < 0 ? 0 : (cy > 31 ? 31 : cy);
  unsigned long long s0, s1, s2, s3, s4, s5, s6;
  s0 = s1 = s2 = s3 = s4 = s5 = s6 = ~0ull;
  for (int r = 0; r < GRID_G; ++r) {
    if (r >= 1 && s6 != ~0ull) {                  // have 7 -> try bound stop
      float bf  = (float)(r - 1) * H_CELL;
      float bd2 = bf * bf * 0.999f - 1e-6f;
      if (bd2 > 0.0f && (unsigned)(s6 >> 32) < sortbits(bd2)) break;
    }
    int y0 = cy - r < 0 ? 0 : cy - r, y1 = cy + r > 31 ? 31 : cy + r;
    int x0 = cx - r < 0 ? 0 : cx - r, x1 = cx + r > 31 ? 31 : cx + r;
    for (int cyy = y0; cyy <= y1; ++cyy) {
      for (int cxx = x0; cxx <= x1; ++cxx) {
        int ax = cxx - cx; ax = ax < 0 ? -ax : ax;
        int ay = cyy - cy; ay = ay < 0 ? -ay : ay;
        if ((ax > ay ? ax : ay) != r) continue;   // perimeter only
        const int cell = cyy * GRID_G + cxx;
        const int pe = cellStart[cell + 1];
        for (int p = cellStart[cell]; p < pe; ++p) {
          const float px = sortXY[p * 2 + 0], py = sortXY[p * 2 + 1];
          const float sqj = px * px + py * py;    // no contract
          const float dot = fmaf(yi, py, xi * px);
          const float d2  = (sqi + sqj) - 2.0f * dot;
          const unsigned long long c =
              (((unsigned long long)sortbits(d2)) << 32) | (unsigned)sortIdx[p];
          if (c < s6) {
            s6 = umin64(s6, umax64(s5, c));
            s5 = umin64(s5, umax64(s4, c));
            s4 = umin64(s4, umax64(s3, c));
            s3 = umin64(s3, umax64(s2, c));
            s2 = umin64(s2, umax64(s1, c));
            s1 = umin64(s1, umax64(s0, c));
            s0 = umin64(s0, c);
          }
        }
      }
    }
  }
  nbr[i * K_NBR + 0] = (int)(s1 & 0xFFFFFFFFu);   // drop rank-0 (self-ish)
  nbr[i * K_NBR + 1] = (int)(s2 & 0xFFFFFFFFu);
  nbr[i * K_NBR + 2] = (int)(s3 & 0xFFFFFFFFu);
  nbr[i * K_NBR + 3] = (int)(s4 & 0xFFFFFFFFu);
  nbr[i * K_NBR + 4] = (int)(s5 & 0xFFFFFFFFu);
  nbr[i * K_NBR + 5] = (int)(s6 & 0xFFFFFFFFu);
}

// ---------- K3: reverse adjacency ----------
__global__ __launch_bounds__(256) void build_inlist_kernel(const int* __restrict__ nbr,
                                                           int* __restrict__ cnt,
                                                           int* __restrict__ inlist) {
  int t = blockIdx.x * 256 + threadIdx.x;
  if (t >= N_EDGE) return;
  int d = (t < KNN_EDGE) ? nbr[t] : (t - KNN_EDGE);
  int p = atomicAdd(&cnt[d], 1);
  if (p < CAP) inlist[(size_t)d * 64 + p] = t;
}

// ---------- K4: bf16 MFMA GEMM ----------
__global__ __launch_bounds__(256) void gemm_kernel(const unsigned short* __restrict__ A,
                                                   const unsigned short* __restrict__ Bt,
                                                   const float* __restrict__ bias,
                                                   float* __restrict__ Cout) {
  __shared__ unsigned short As[128 * 32];
  __shared__ unsigned short Bs[128 * 32];
  const int tid = threadIdx.x, lane = tid & 63, wave = tid >> 6;
  const int bn0 = blockIdx.x * 128, bm0 = blockIdx.y * 128;
  const int wr = wave >> 1, wc = wave & 1;
  f32x4 acc[4][4];
#pragma unroll
  for (int m = 0; m < 4; ++m)
#pragma unroll
    for (int n = 0; n < 4; ++n) acc[m][n] = (f32x4)0.0f;

  const int rs = wave * 32 + (lane >> 2);
  for (int k0 = 0; k0 < 512; k0 += 32) {
    __syncthreads();
#pragma unroll
    for (int q = 0; q < 2; ++q) {
      int r  = rs + q * 16;
      int cc = (lane & 3) ^ ((r >> 1) & 3);
      GLOAD_LDS16(A  + (size_t)(bm0 + r) * 512 + k0 + cc * 8, As + (wave * 2 + q) * 512);
      GLOAD_LDS16(Bt + (size_t)(bn0 + r) * 512 + k0 + cc * 8, Bs + (wave * 2 + q) * 512);
    }
    __syncthreads();
    bf16x8 af[4], bfr[4];
#pragma unroll
    for (int m = 0; m < 4; ++m) {
      int r  = wr * 64 + m * 16 + (lane & 15);
      int sl = (lane >> 4) ^ ((r >> 1) & 3);
      af[m] = *(const bf16x8*)(As + r * 32 + sl * 8);
    }
#pragma unroll
    for (int n = 0; n < 4; ++n) {
      int r  = wc * 64 + n * 16 + (lane & 15);
      int sl = (lane >> 4) ^ ((r >> 1) & 3);
      bfr[n] = *(const bf16x8*)(Bs + r * 32 + sl * 8);
    }
#pragma unroll
    for (int m = 0; m < 4; ++m)
#pragma unroll
      for (int n = 0; n < 4; ++n)
        acc[m][n] = __builtin_amdgcn_mfma_f32_16x16x32_bf16(af[m], bfr[n], acc[m][n], 0, 0, 0);
  }
#pragma unroll
  for (int n = 0; n < 4; ++n) {
    int col = bn0 + wc * 64 + n * 16 + (lane & 15);
    float bv = bias[col];
#pragma unroll
    for (int m = 0; m < 4; ++m) {
      int rbase = bm0 + wr * 64 + m * 16 + (lane >> 4) * 4;
#pragma unroll
      for (int g = 0; g < 4; ++g) {
        int row = rbase + g;
        if (row < N_NODES) Cout[(size_t)row * HC + col] = acc[m][n][g] + bv;
      }
    }
  }
}

// ---------- K5: xlW ----------
__global__ __launch_bounds__(256) void xlw_kernel(const float* __restrict__ xl,
                                                  const float* __restrict__ fcW,
                                                  float* __restrict__ xlW) {
  const int wave = threadIdx.x >> 6, lane = threadIdx.x & 63;
  const int idx = blockIdx.x * 4 + wave;          // < 24000 exact
  const int n = idx / 3, h = idx - n * 3;
  const float* row = xl + (size_t)n * HC + h * C_DIM + lane * 8;
  f32x4 a = *(const f32x4*)(row);
  f32x4 b = *(const f32x4*)(row + 4);
  const float* fw = fcW + lane * 16;
  float vv[8] = {a[0], a[1], a[2], a[3], b[0], b[1], b[2], b[3]};
  float s0 = 0.f, s1 = 0.f;
#pragma unroll
  for (int t = 0; t < 8; ++t) { s0 += vv[t] * fw[2 * t]; s1 += vv[t] * fw[2 * t + 1]; }
  s0 = wred_add(s0); s1 = wred_add(s1);
  if (lane == 0) { xlW[(size_t)idx * 2] = s0; xlW[(size_t)idx * 2 + 1] = s1; }
}

__global__ void const2_kernel(const float* __restrict__ gb, const float* __restrict__ fcW,
                              const float* __restrict__ fcb, float* __restrict__ cb) {
  const int lane = threadIdx.x;                   // block 64
  const float* g = gb + lane * 8;
  const float* fw = fcW + lane * 16;
  float s0 = 0.f, s1 = 0.f;
#pragma unroll
  for (int t = 0; t < 8; ++t) { s0 += g[t] * fw[2 * t]; s1 += g[t] * fw[2 * t + 1]; }
  s0 = wred_add(s0); s1 = wred_add(s1);
  if (lane == 0) { cb[0] = s0 + fcb[0]; cb[1] = s1 + fcb[1]; }
}

// ---------- K6a: edge-parallel e-values ----------
__global__ __launch_bounds__(256) void edge_e_kernel(const float* __restrict__ xl,
                                                     const float* __restrict__ xr,
                                                     const float* __restrict__ att,
                                                     const int* __restrict__ nbr,
                                                     float* __restrict__ eval) {
  const int wave = threadIdx.x >> 6, lane = threadIdx.x & 63;
  const int e = blockIdx.x * 4 + wave;            // grid 14000 -> e < 56000 exact
  const int s = (e < KNN_EDGE) ? (e / K_NBR) : (e - KNN_EDGE);
  const int d = (e < KNN_EDGE) ? nbr[e] : (e - KNN_EDGE);
  const int c0 = lane * 8;
  float o[3];
#pragma unroll
  for (int h = 0; h < 3; ++h) {
    const float* xla = xl + (size_t)s * HC + h * C_DIM + c0;
    const float* xra = xr + (size_t)d * HC + h * C_DIM + c0;
    const float* ata = att + h * C_DIM + c0;
    f32x4 a0 = *(const f32x4*)(xla);
    f32x4 a1 = *(const f32x4*)(xla + 4);
    f32x4 r0 = *(const f32x4*)(xra);
    f32x4 r1 = *(const f32x4*)(xra + 4);
    f32x4 t0 = *(const f32x4*)(ata);
    f32x4 t1 = *(const f32x4*)(ata + 4);
    float p = 0.f;
#pragma unroll
    for (int j = 0; j < 4; ++j) {
      float v = r0[j] + a0[j];
      v = (v >= 0.f) ? v : v * NEG_SLOPE;
      p += v * t0[j];
    }
#pragma unroll
    for (int j = 0; j < 4; ++j) {
      float v = r1[j] + a1[j];
      v = (v >= 0.f) ? v : v * NEG_SLOPE;
      p += v * t1[j];
    }
    o[h] = wred_add(p);
  }
  if (lane == 0) {
    eval[(size_t)e * 3 + 0] = o[0];
    eval[(size_t)e * 3 + 1] = o[1];
    eval[(size_t)e * 3 + 2] = o[2];
  }
}

// ---------- K6b: per-dst softmax + aggregation + fc ----------
__global__ __launch_bounds__(256) void softmax_agg_kernel(const int* __restrict__ cnt,
                                                          const int* __restrict__ inlist,
                                                          const float* __restrict__ eval,
                                                          const float* __restrict__ xlW,
                                                          const float* __restrict__ cb,
                                                          float* __restrict__ out) {
  const int wave = threadIdx.x >> 6, lane = threadIdx.x & 63;
  const int d = blockIdx.x * 4 + wave;            // grid 2000 -> d < 8000 exact
  int cn = cnt[d]; if (cn > CAP) cn = CAP;
  int idl = (lane < cn) ? inlist[(size_t)d * 64 + lane] : 0;
  int sl  = (idl < KNN_EDGE) ? (idl / K_NBR) : (idl - KNN_EDGE);
  float o0 = 0.f, o1 = 0.f;
#pragma unroll
  for (int h = 0; h < 3; ++h) {
    float ev = (lane < cn) ? eval[(size_t)idl * 3 + h] : -__builtin_inff();
    float mx = wred_max(ev);
    float ex = (lane < cn) ? expf(ev - mx) : 0.f;
    float ss = wred_add(ex);
    float alpha = ex / (ss + 1e-16f);
    float w0 = (lane < cn) ? xlW[((size_t)sl * 3 + h) * 2]     * alpha : 0.f;
    float w1 = (lane < cn) ? xlW[((size_t)sl * 3 + h) * 2 + 1] * alpha : 0.f;
    o0 += wred_add(w0);
    o1 += wred_add(w1);
  }
  if (lane == 0) {
    out[d * 2]     = o0 * (1.0f / 3.0f) + cb[0];
    out[d * 2 + 1] = o1 * (1.0f / 3.0f) + cb[1];
  }
}

// ---------- launch ----------
extern "C" void kernel_launch(void* const* d_in, const int* in_sizes, int n_in,
                              void* d_out, int out_size, void* d_ws, size_t ws_size,
                              hipStream_t stream) {
  const float* feature  = (const float*)d_in[0];
  const float* position = (const float*)d_in[1];
  const float* W_l      = (const float*)d_in[2];
  const float* b_l      = (const float*)d_in[3];
  const float* W_r      = (const float*)d_in[4];
  const float* b_r      = (const float*)d_in[5];
  const float* att      = (const float*)d_in[6];
  const float* gat_bias = (const float*)d_in[7];
  const float* fc_W     = (const float*)d_in[8];
  const float* fc_b     = (const float*)d_in[9];
  float* out = (float*)d_out;

  if (ws_size < WS_NEED) return;  // need ~113.1 MB scratch

  uint8_t* ws = (uint8_t*)d_ws;
  unsigned short* xb  = (unsigned short*)(ws + XB_OFF);
  unsigned short* wt0 = (unsigned short*)(ws + WT_OFF);
  unsigned short* wt1 = wt0 + (size_t)1536 * 512;
  float* xl    = (float*)(ws + XL_OFF);
  float* xr    = (float*)(ws + XR_OFF);
  int*   nbr   = (int*)(ws + NBR_OFF);
  int*   cnt   = (int*)(ws + CNT_OFF);
  int*   inl   = (int*)(ws + INL_OFF);
  float* xlW   = (float*)(ws + XLW_OFF);
  float* cb    = (float*)(ws + CB_OFF);
  float* ev    = (float*)(ws + EV_OFF);
  int*   ccnt  = (int*)(ws + CCNT_OFF);
  int*   cst   = (int*)(ws + CST_OFF);
  int*   slot  = (int*)(ws + SLOT_OFF);
  int*   sidx  = (int*)(ws + SIDX_OFF);
  float* sxy   = (float*)(ws + SXY_OFF);

  hipMemsetAsync(cnt, 0, (size_t)N_NODES * 4, stream);
  hipMemsetAsync(ccnt, 0, 1024 * 4, stream);

  convert_x_kernel<<<4000, 256, 0, stream>>>(feature, xb);
  convert_w_kernel<<<3072, 256, 0, stream>>>(W_l, wt0);
  convert_w_kernel<<<3072, 256, 0, stream>>>(W_r, wt1);
  cellcnt_kernel<<<32, 256, 0, stream>>>(position, ccnt, slot);
  scan_kernel<<<1, 256, 0, stream>>>(ccnt, cst);
  scatter_kernel<<<32, 256, 0, stream>>>(position, cst, slot, sidx, sxy);
  knn_kernel<<<32, 256, 0, stream>>>(position, cst, sidx, sxy, nbr);
  build_inlist_kernel<<<219, 256, 0, stream>>>(nbr, cnt, inl);
  gemm_kernel<<<dim3(12, 63), 256, 0, stream>>>(xb, wt0, b_l, xl);
  gemm_kernel<<<dim3(12, 63), 256, 0, stream>>>(xb, wt1, b_r, xr);
  xlw_kernel<<<6000, 256, 0, stream>>>(xl, fc_W, xlW);
  const2_kernel<<<1, 64, 0, stream>>>(gat_bias, fc_W, fc_b, cb);
  edge_e_kernel<<<14000, 256, 0, stream>>>(xl, xr, att, nbr, ev);
  softmax_agg_kernel<<<2000, 256, 0, stream>>>(cnt, inl, ev, xlW, cb, out);
}